// Round 1
// baseline (671.707 us; speedup 1.0000x reference)
//
#include <hip/hip_runtime.h>

// Correlation layer: out[b, dy*9+dx, y, x] =
//   (1/256) * sum_c frn[b,c,y,x] * fqn_pad[b,c,y+dy,x+dx]   (pad r=4)
// Identity used: dot(frn,fqn) = dot(fr,fq) / (max(|fr|,eps)*max(|fq|,eps))
// so we accumulate raw dots + per-pixel sum-of-squares in one fused pass.

#define BB 8
#define CC 256
#define HH 96
#define WW 128
#define HW (HH*WW)
#define CHW (CC*HW)
#define NDISP 81
#define TXS 64          // tile width  (16 threads x * 4 px)
#define TYS 8           // tile height (4 threads y * 2 px)
#define HXF 72          // halo width in floats (TXS + 8)
#define HX4 18          // halo width in float4
#define HR 9            // halo rows staged per dy-group (TYS + 2 - 1)
#define NSLOT (HR*HX4)  // 162 float4 slots per channel
#define CK 4            // channels per LDS chunk
#define YT 12           // H / TYS
#define XT 2            // W / TXS
#define NTILES (BB*YT*XT) // 192
#define NGRP 5          // dy groups: d0 = 0,2,4,6,8
#define EPSN 1e-12f

__global__ __launch_bounds__(64, 2) void corr_kernel(
    const float* __restrict__ fr, const float* __restrict__ fq,
    float* __restrict__ out)
{
    __shared__ float4 s_fq[CK * NSLOT];   // [CK][HR][HX4] staged fq halo
    __shared__ float4 s_nq4[NSLOT];       // [HR][HX4] inv-norms of fq halo px

    const int tid = threadIdx.x;
    const int tx  = tid & 15;   // 0..15
    const int ty  = tid >> 4;   // 0..3

    const int tile = blockIdx.x % NTILES;  // same-tile groups: stride 192 ≡ 0 mod 8 → same XCD
    const int g    = blockIdx.x / NTILES;  // 0..4
    const int d0   = g * 2;                // dy group base
    const int b    = tile / (YT * XT);
    const int rem  = tile % (YT * XT);
    const int y0   = (rem >> 1) * TYS;
    const int x0   = (rem & 1) * TXS;

    // ---- fq staging slot ownership (fixed per thread → per-pixel sq sums) ----
    int  sslot[3]; bool sact[3]; bool sval[3]; int sgbase[3];
#pragma unroll
    for (int k = 0; k < 3; ++k) {
        int s = tid + 64 * k;
        sslot[k] = s;
        sact[k]  = (s < NSLOT);
        int row  = s / HX4;
        int col4 = s % HX4;
        int gy = y0 + d0 - 4 + row;
        int gx = x0 - 4 + col4 * 4;
        sval[k]   = sact[k] && ((unsigned)gy < (unsigned)HH) && ((unsigned)gx < (unsigned)WW);
        sgbase[k] = b * CHW + gy * WW + gx;   // + c*HW per channel (guarded by sval)
    }

    const int trow0   = y0 + ty * 2;
    const int frbase0 = b * CHW + (trow0    ) * WW + x0 + tx * 4;
    const int frbase1 = b * CHW + (trow0 + 1) * WW + x0 + tx * 4;

    float4 acc[2][2][9];   // [pyi][dyi][dx], each float4 = 4 px in x
#pragma unroll
    for (int i = 0; i < 2; ++i)
#pragma unroll
        for (int j = 0; j < 2; ++j)
#pragma unroll
            for (int d = 0; d < 9; ++d)
                acc[i][j][d] = make_float4(0.f, 0.f, 0.f, 0.f);

    float4 fr2[2] = {make_float4(0.f,0.f,0.f,0.f), make_float4(0.f,0.f,0.f,0.f)};
    float4 sqq[3] = {make_float4(0.f,0.f,0.f,0.f), make_float4(0.f,0.f,0.f,0.f),
                     make_float4(0.f,0.f,0.f,0.f)};

#pragma unroll 1
    for (int c0 = 0; c0 < CC; c0 += CK) {
        __syncthreads();   // previous chunk's LDS reads done
        // ---- stage fq halo chunk (float4, coalesced) + accumulate fq^2 ----
#pragma unroll
        for (int k = 0; k < 3; ++k) {
            if (sact[k]) {
#pragma unroll
                for (int c = 0; c < CK; ++c) {
                    float4 v = make_float4(0.f, 0.f, 0.f, 0.f);
                    if (sval[k])
                        v = *(const float4*)(fq + sgbase[k] + (c0 + c) * HW);
                    s_fq[c * NSLOT + sslot[k]] = v;
                    sqq[k].x += v.x * v.x;
                    sqq[k].y += v.y * v.y;
                    sqq[k].z += v.z * v.z;
                    sqq[k].w += v.w * v.w;
                }
            }
        }
        __syncthreads();

        // ---- compute ----
#pragma unroll
        for (int c = 0; c < CK; ++c) {
            float4 a0 = *(const float4*)(fr + frbase0 + (c0 + c) * HW);
            float4 a1 = *(const float4*)(fr + frbase1 + (c0 + c) * HW);
            fr2[0].x += a0.x * a0.x; fr2[0].y += a0.y * a0.y;
            fr2[0].z += a0.z * a0.z; fr2[0].w += a0.w * a0.w;
            fr2[1].x += a1.x * a1.x; fr2[1].y += a1.y * a1.y;
            fr2[1].z += a1.z * a1.z; fr2[1].w += a1.w * a1.w;

            float rw[3][12];
#pragma unroll
            for (int j = 0; j < 3; ++j) {
#pragma unroll
                for (int s4 = 0; s4 < 3; ++s4) {
                    float4 t = s_fq[c * NSLOT + (ty * 2 + j) * HX4 + tx + s4];
                    rw[j][s4 * 4 + 0] = t.x;
                    rw[j][s4 * 4 + 1] = t.y;
                    rw[j][s4 * 4 + 2] = t.z;
                    rw[j][s4 * 4 + 3] = t.w;
                }
            }
#pragma unroll
            for (int pyi = 0; pyi < 2; ++pyi) {
                float4 av = pyi ? a1 : a0;
#pragma unroll
                for (int dyi = 0; dyi < 2; ++dyi) {
                    const float* rr = rw[pyi + dyi];
#pragma unroll
                    for (int dx = 0; dx < 9; ++dx) {
                        acc[pyi][dyi][dx].x += av.x * rr[dx + 0];
                        acc[pyi][dyi][dx].y += av.y * rr[dx + 1];
                        acc[pyi][dyi][dx].z += av.z * rr[dx + 2];
                        acc[pyi][dyi][dx].w += av.w * rr[dx + 3];
                    }
                }
            }
        }
    }

    // ---- epilogue: inv-norms, then normalized stores ----
#pragma unroll
    for (int k = 0; k < 3; ++k) {
        if (sact[k]) {
            float4 q;
            q.x = 1.0f / fmaxf(sqrtf(sqq[k].x), EPSN);
            q.y = 1.0f / fmaxf(sqrtf(sqq[k].y), EPSN);
            q.z = 1.0f / fmaxf(sqrtf(sqq[k].z), EPSN);
            q.w = 1.0f / fmaxf(sqrtf(sqq[k].w), EPSN);
            s_nq4[sslot[k]] = q;
        }
    }
    __syncthreads();
    const float* s_nq = (const float*)s_nq4;

    float4 ir[2];
#pragma unroll
    for (int pyi = 0; pyi < 2; ++pyi) {
        ir[pyi].x = 1.0f / fmaxf(sqrtf(fr2[pyi].x), EPSN);
        ir[pyi].y = 1.0f / fmaxf(sqrtf(fr2[pyi].y), EPSN);
        ir[pyi].z = 1.0f / fmaxf(sqrtf(fr2[pyi].z), EPSN);
        ir[pyi].w = 1.0f / fmaxf(sqrtf(fr2[pyi].w), EPSN);
    }

    const float inv256 = 1.0f / 256.0f;
#pragma unroll
    for (int pyi = 0; pyi < 2; ++pyi) {
        const int tr = ty * 2 + pyi;
#pragma unroll
        for (int dyi = 0; dyi < 2; ++dyi) {
            const int dy = d0 + dyi;
            if (dy > 8) continue;   // group 4 has only dy=8 (uniform branch)
            const float* nrow = s_nq + (tr + dyi) * HXF + tx * 4;
#pragma unroll
            for (int dx = 0; dx < 9; ++dx) {
                float4 a = acc[pyi][dyi][dx];
                float4 o;
                o.x = a.x * ir[pyi].x * nrow[dx + 0] * inv256;
                o.y = a.y * ir[pyi].y * nrow[dx + 1] * inv256;
                o.z = a.z * ir[pyi].z * nrow[dx + 2] * inv256;
                o.w = a.w * ir[pyi].w * nrow[dx + 3] * inv256;
                *(float4*)(out + ((size_t)(b * NDISP + dy * 9 + dx) * HH + (y0 + tr)) * WW
                                 + x0 + tx * 4) = o;
            }
        }
    }
}

extern "C" void kernel_launch(void* const* d_in, const int* in_sizes, int n_in,
                              void* d_out, int out_size, void* d_ws, size_t ws_size,
                              hipStream_t stream) {
    const float* fr = (const float*)d_in[0];
    const float* fq = (const float*)d_in[1];
    float* out = (float*)d_out;
    corr_kernel<<<dim3(NTILES * NGRP), dim3(64), 0, stream>>>(fr, fq, out);
}

// Round 2
// 422.262 us; speedup vs baseline: 1.5907x; 1.5907x over previous
//
#include <hip/hip_runtime.h>

// Correlation layer: out[b, dy*9+dx, y, x] =
//   (1/256) * sum_c frn[b,c,y,x] * fqn_pad[b,c,y+dy,x+dx]   (pad r=4)
// Identity: dot(frn,fqn) = dot(fr,fq) * invnorm(fr) * invnorm(fq),
// so raw dots + per-pixel sum-of-squares accumulate in one fused pass.
//
// R2 restructure: 2-wave blocks, 1 dy per block, 9 dy-groups.
// 3456 waves (~13.5/CU) vs R1's 960 (~3.75/CU) — R1 was latency-bound
// (HBM 6.6% peak, 1 wave/SIMD, all ds_read/vmcnt/barrier stalls exposed).

#define BB 8
#define CC 256
#define HH 96
#define WW 128
#define HW (HH*WW)
#define CHW (CC*HW)
#define NDISP 81
#define TXS 64          // tile width  (16 threads x * 4 px)
#define TYS 8           // tile height (8 thread rows * 1 px)
#define HXF 72          // halo width in floats (TXS + 8)
#define HX4 18          // halo width in float4
#define NSLOT (TYS*HX4) // 144 float4 slots per channel (8 halo rows)
#define CK 4            // channels per LDS chunk
#define YT 12           // H / TYS
#define XT 2            // W / TXS
#define NTILES (BB*YT*XT) // 192
#define NGRP 9          // one dy per group
#define NTHR 128        // 2 waves
#define EPSN 1e-12f

__global__ __launch_bounds__(NTHR, 4) void corr_kernel(
    const float* __restrict__ fr, const float* __restrict__ fq,
    float* __restrict__ out)
{
    __shared__ float4 s_fq[CK * NSLOT];   // [CK][8 rows][HX4] staged fq halo
    __shared__ float4 s_nq4[NSLOT];       // inv-norms of fq halo px

    const int tid = threadIdx.x;
    const int tx  = tid & 15;   // 0..15 (x, *4 px)
    const int ty  = tid >> 4;   // 0..7  (row)

    const int tile = blockIdx.x % NTILES;  // same-tile groups at stride 192 ≡ 0 mod 8 → same XCD
    const int dy   = blockIdx.x / NTILES;  // 0..8
    const int b    = tile / (YT * XT);
    const int rem  = tile % (YT * XT);
    const int y0   = (rem >> 1) * TYS;
    const int x0   = (rem & 1) * TXS;

    // ---- fq staging slot ownership (fixed per thread → per-pixel sq sums) ----
    // k=0: slot = tid (all 128);  k=1: slot = 128+tid (tid<16 only)
    int  sslot[2]; bool sact[2]; bool sval[2]; int sgbase[2];
#pragma unroll
    for (int k = 0; k < 2; ++k) {
        int s = tid + NTHR * k;
        sslot[k] = s;
        sact[k]  = (s < NSLOT);
        int row  = s / HX4;          // halo row = output row offset
        int col4 = s % HX4;
        int gy = y0 + dy - 4 + row;  // fq row for output row y0+row at this dy
        int gx = x0 - 4 + col4 * 4;
        sval[k]   = sact[k] && ((unsigned)gy < (unsigned)HH) && ((unsigned)gx < (unsigned)WW);
        sgbase[k] = b * CHW + gy * WW + gx;   // + c*HW per channel (guarded by sval)
    }

    const int frbase = b * CHW + (y0 + ty) * WW + x0 + tx * 4;

    float4 acc[9];   // [dx], each float4 = 4 px in x
#pragma unroll
    for (int d = 0; d < 9; ++d) acc[d] = make_float4(0.f, 0.f, 0.f, 0.f);

    float4 fr2 = make_float4(0.f, 0.f, 0.f, 0.f);
    float4 sqq[2] = {make_float4(0.f,0.f,0.f,0.f), make_float4(0.f,0.f,0.f,0.f)};

#pragma unroll 1
    for (int c0 = 0; c0 < CC; c0 += CK) {
        __syncthreads();   // previous chunk's LDS reads done
        // ---- stage fq halo chunk (float4, coalesced) + accumulate fq^2 ----
#pragma unroll
        for (int k = 0; k < 2; ++k) {
            if (sact[k]) {
#pragma unroll
                for (int c = 0; c < CK; ++c) {
                    float4 v = make_float4(0.f, 0.f, 0.f, 0.f);
                    if (sval[k])
                        v = *(const float4*)(fq + sgbase[k] + (c0 + c) * HW);
                    s_fq[c * NSLOT + sslot[k]] = v;
                    sqq[k].x += v.x * v.x;
                    sqq[k].y += v.y * v.y;
                    sqq[k].z += v.z * v.z;
                    sqq[k].w += v.w * v.w;
                }
            }
        }
        __syncthreads();

        // ---- compute ----
#pragma unroll
        for (int c = 0; c < CK; ++c) {
            float4 a = *(const float4*)(fr + frbase + (c0 + c) * HW);
            fr2.x += a.x * a.x; fr2.y += a.y * a.y;
            fr2.z += a.z * a.z; fr2.w += a.w * a.w;

            float rw[12];
#pragma unroll
            for (int s4 = 0; s4 < 3; ++s4) {
                float4 t = s_fq[c * NSLOT + ty * HX4 + tx + s4];
                rw[s4 * 4 + 0] = t.x;
                rw[s4 * 4 + 1] = t.y;
                rw[s4 * 4 + 2] = t.z;
                rw[s4 * 4 + 3] = t.w;
            }
#pragma unroll
            for (int dx = 0; dx < 9; ++dx) {
                acc[dx].x += a.x * rw[dx + 0];
                acc[dx].y += a.y * rw[dx + 1];
                acc[dx].z += a.z * rw[dx + 2];
                acc[dx].w += a.w * rw[dx + 3];
            }
        }
    }

    // ---- epilogue: inv-norms, then normalized stores ----
#pragma unroll
    for (int k = 0; k < 2; ++k) {
        if (sact[k]) {
            float4 q;
            q.x = 1.0f / fmaxf(sqrtf(sqq[k].x), EPSN);
            q.y = 1.0f / fmaxf(sqrtf(sqq[k].y), EPSN);
            q.z = 1.0f / fmaxf(sqrtf(sqq[k].z), EPSN);
            q.w = 1.0f / fmaxf(sqrtf(sqq[k].w), EPSN);
            s_nq4[sslot[k]] = q;
        }
    }
    __syncthreads();
    const float* s_nq = (const float*)s_nq4;

    float4 ir;
    ir.x = 1.0f / fmaxf(sqrtf(fr2.x), EPSN);
    ir.y = 1.0f / fmaxf(sqrtf(fr2.y), EPSN);
    ir.z = 1.0f / fmaxf(sqrtf(fr2.z), EPSN);
    ir.w = 1.0f / fmaxf(sqrtf(fr2.w), EPSN);

    const float inv256 = 1.0f / 256.0f;
    const float* nrow = s_nq + ty * HXF + tx * 4;
#pragma unroll
    for (int dx = 0; dx < 9; ++dx) {
        float4 a = acc[dx];
        float4 o;
        o.x = a.x * ir.x * nrow[dx + 0] * inv256;
        o.y = a.y * ir.y * nrow[dx + 1] * inv256;
        o.z = a.z * ir.z * nrow[dx + 2] * inv256;
        o.w = a.w * ir.w * nrow[dx + 3] * inv256;
        *(float4*)(out + ((size_t)(b * NDISP + dy * 9 + dx) * HH + (y0 + ty)) * WW
                         + x0 + tx * 4) = o;
    }
}

extern "C" void kernel_launch(void* const* d_in, const int* in_sizes, int n_in,
                              void* d_out, int out_size, void* d_ws, size_t ws_size,
                              hipStream_t stream) {
    const float* fr = (const float*)d_in[0];
    const float* fq = (const float*)d_in[1];
    float* out = (float*)d_out;
    corr_kernel<<<dim3(NTILES * NGRP), dim3(NTHR), 0, stream>>>(fr, fq, out);
}